// Round 4
// baseline (406.256 us; speedup 1.0000x reference)
//
#include <hip/hip_runtime.h>

#define H 320
#define W 320
#define OH 314
#define OW 314
#define NIMG 256       // 32 batch * 8 channels
#define SOUT 16        // output rows per wave-strip
#define NSTRIP 20      // 20*16 = 320 >= 314
#define NGRP 3         // column groups; each wave covers 122 output cols
#define GRPW 122
#define NBLK 5         // blocks per (img,grp): 5 blocks * 4 waves = 20 strips
#define NBLOCKS (NIMG * NGRP * NBLK)   // 3840

__device__ __forceinline__ float ssim_val(float sxs, float sys, float sxxs,
                                          float syys, float sxys,
                                          float w0, float C1, float C2) {
    const float COV = 49.0f / 48.0f;
    float ux  = sxs  * w0, uy  = sys  * w0;
    float uxx = sxxs * w0, uyy = syys * w0, uxy = sxys * w0;
    float vx  = COV * (uxx - ux * ux);
    float vy  = COV * (uyy - uy * uy);
    float vxy = COV * (uxy - ux * uy);
    float A1 = 2.f * ux * uy + C1;
    float A2 = 2.f * vxy + C2;
    float B1 = ux * ux + uy * uy + C1;
    float B2 = vx + vy + C2;
    float den = B1 * B2 + 1e-8f;
    float inv = __builtin_amdgcn_rcpf(den);
    inv = inv * (2.f - den * inv);          // one Newton step
    return (A1 * A2) * inv;
}

// horizontal 7-window sums from per-lane float2 vertical sums, 3 shuffles:
// t = P + P(+1) covers cols 2l..2l+3; S8 = t + t(+2) covers 2l..2l+7;
// even window = S8 - col(2l+7);  odd window = S8 - col(2l).
#define HSUM3(v2, e, o)                                  \
{                                                        \
    float P_ = v2.x + v2.y;                              \
    float t_ = P_ + __shfl_down(P_, 1);                  \
    float S8 = t_ + __shfl_down(t_, 2);                  \
    float o3 = __shfl_down(v2.y, 3);                     \
    e = S8 - o3;                                         \
    o = S8 - v2.x;                                       \
}

#define ROW_BODY(P, I, DOEMIT)                                             \
{                                                                          \
    const int rr   = min(r0 + (I), H - 1);                                 \
    const int rofs = rr * W + cl;                                          \
    const float2 xn = *(const float2*)(Xb + rofs);                         \
    const float2 yn = *(const float2*)(Yb + rofs);                         \
    const float2 xo = rx[P];                                               \
    const float2 yo = ry[P];                                               \
    sx.x  += xn.x - xo.x;            sx.y  += xn.y - xo.y;                 \
    sy.x  += yn.x - yo.x;            sy.y  += yn.y - yo.y;                 \
    sxx.x += xn.x*xn.x - xo.x*xo.x;  sxx.y += xn.y*xn.y - xo.y*xo.y;       \
    syy.x += yn.x*yn.x - yo.x*yo.x;  syy.y += yn.y*yn.y - yo.y*yo.y;       \
    sxy.x += xn.x*yn.x - xo.x*yo.x;  sxy.y += xn.y*yn.y - xo.y*yo.y;       \
    rx[P] = xn; ry[P] = yn;                                                \
    if (DOEMIT) {                                                          \
        const int orow = r0 + (I) - 6;                                     \
        if (orow < OH) {                                                   \
            float ex, oxv, ey, oyv, exx, oxx, eyy, oyy, exy, oxy;          \
            HSUM3(sx,  ex,  oxv)                                           \
            HSUM3(sy,  ey,  oyv)                                           \
            HSUM3(sxx, exx, oxx)                                           \
            HSUM3(syy, eyy, oyy)                                           \
            HSUM3(sxy, exy, oxy)                                           \
            float S0 = ssim_val(ex,  ey,  exx, eyy, exy, w0, C1, C2);      \
            float S1 = ssim_val(oxv, oyv, oxx, oyy, oxy, w0, C1, C2);      \
            acc += (v0ok ? S0 : 0.f) + (v1ok ? S1 : 0.f);                  \
        }                                                                  \
    }                                                                      \
}

__global__ __launch_bounds__(256) void ssim_slide_kernel(
    const float* __restrict__ X, const float* __restrict__ Y,
    const float* __restrict__ dr_p, const float* __restrict__ w_p,
    double* __restrict__ accum, unsigned int* __restrict__ ticket,
    float* __restrict__ out)
{
    const int t    = threadIdx.x;
    const int lane = t & 63;
    const int wave = t >> 6;

    // grid: NIMG * NGRP * NBLK blocks; each block = 4 waves = 4 strips
    const int bid = blockIdx.x;
    const int img = bid / (NGRP * NBLK);
    const int rem = bid - img * (NGRP * NBLK);
    const int grp = rem / NBLK;
    const int blk = rem - grp * NBLK;
    const int strip = blk * 4 + wave;           // 0..19
    const int r0    = strip * SOUT;             // first output row of strip

    const int cbase = grp * GRPW;
    const int c0 = cbase + 2 * lane;            // even input col owned by lane
    const int cl = min(c0, W - 2);              // clamp for safe float2 load

    const float* __restrict__ Xb = X + (size_t)img * (H * W);
    const float* __restrict__ Yb = Y + (size_t)img * (H * W);

    const float dr = dr_p[0];
    const float w0 = w_p[0];                    // uniform 1/49 weight
    const float C1 = (0.01f * dr) * (0.01f * dr);
    const float C2 = (0.03f * dr) * (0.03f * dr);

    const bool v0ok = (lane <= 60) && (c0     < OW);
    const bool v1ok = (lane <= 60) && (c0 + 1 < OW);

    float2 rx[7], ry[7];
#pragma unroll
    for (int i = 0; i < 7; ++i) { rx[i] = make_float2(0.f, 0.f); ry[i] = make_float2(0.f, 0.f); }
    float2 sx  = make_float2(0.f, 0.f), sy  = make_float2(0.f, 0.f);
    float2 sxx = make_float2(0.f, 0.f), syy = make_float2(0.f, 0.f);
    float2 sxy = make_float2(0.f, 0.f);
    float acc = 0.f;

    // 22 input rows, phases I%7; rows 6..21 emit output rows r0..r0+15
    ROW_BODY(0, 0,  false)
    ROW_BODY(1, 1,  false)
    ROW_BODY(2, 2,  false)
    ROW_BODY(3, 3,  false)
    ROW_BODY(4, 4,  false)
    ROW_BODY(5, 5,  false)
    ROW_BODY(6, 6,  true)
    ROW_BODY(0, 7,  true)
    ROW_BODY(1, 8,  true)
    ROW_BODY(2, 9,  true)
    ROW_BODY(3, 10, true)
    ROW_BODY(4, 11, true)
    ROW_BODY(5, 12, true)
    ROW_BODY(6, 13, true)
    ROW_BODY(0, 14, true)
    ROW_BODY(1, 15, true)
    ROW_BODY(2, 16, true)
    ROW_BODY(3, 17, true)
    ROW_BODY(4, 18, true)
    ROW_BODY(5, 19, true)
    ROW_BODY(6, 20, true)
    ROW_BODY(0, 21, true)

    // wave reduce
#pragma unroll
    for (int off = 32; off > 0; off >>= 1)
        acc += __shfl_down(acc, off);

    __shared__ float wsum[4];
    if (lane == 0) wsum[wave] = acc;
    __syncthreads();
    if (t == 0) {
        float s = wsum[0] + wsum[1] + wsum[2] + wsum[3];
        atomicAdd(accum, (double)s);
        __threadfence();
        unsigned int prev = atomicAdd(ticket, 1u);
        if (prev == (unsigned int)(NBLOCKS - 1)) {
            // all other blocks' accum adds are fence-ordered before their
            // ticket adds -> visible here; read via device-scope RMW
            double tot = atomicAdd(accum, 0.0);
            const double cnt = (double)NIMG * (double)(OH * OW);
            out[0] = 1.0f - (float)(tot / cnt);
        }
    }
}

extern "C" void kernel_launch(void* const* d_in, const int* in_sizes, int n_in,
                              void* d_out, int out_size, void* d_ws, size_t ws_size,
                              hipStream_t stream) {
    const float* X  = (const float*)d_in[0];
    const float* Y  = (const float*)d_in[1];
    const float* dr = (const float*)d_in[2];
    const float* w  = (const float*)d_in[3];
    double* accum        = (double*)d_ws;
    unsigned int* ticket = (unsigned int*)((char*)d_ws + 8);
    float* out           = (float*)d_out;

    hipMemsetAsync(d_ws, 0, 16, stream);

    ssim_slide_kernel<<<NBLOCKS, 256, 0, stream>>>(X, Y, dr, w, accum, ticket, out);
}

// Round 5
// 246.959 us; speedup vs baseline: 1.6450x; 1.6450x over previous
//
#include <hip/hip_runtime.h>

#define H 320
#define W 320
#define OH 314
#define OW 314
#define NIMG 256       // 32 batch * 8 channels
#define SOUT 16        // output rows per wave-strip
#define NSTRIP 20      // 20*16 = 320 >= 314
#define NGRP 3         // column groups; each wave covers 122 output cols
#define GRPW 122
#define NBLK 5         // blocks per (img,grp): 5 blocks * 4 waves = 20 strips
#define NBLOCKS (NIMG * NGRP * NBLK)   // 3840

__device__ __forceinline__ float ssim_val(float sxs, float sys, float sxxs,
                                          float syys, float sxys,
                                          float w0, float C1, float C2) {
    const float COV = 49.0f / 48.0f;
    float ux  = sxs  * w0, uy  = sys  * w0;
    float uxx = sxxs * w0, uyy = syys * w0, uxy = sxys * w0;
    float vx  = COV * (uxx - ux * ux);
    float vy  = COV * (uyy - uy * uy);
    float vxy = COV * (uxy - ux * uy);
    float A1 = 2.f * ux * uy + C1;
    float A2 = 2.f * vxy + C2;
    float B1 = ux * ux + uy * uy + C1;
    float B2 = vx + vy + C2;
    float den = B1 * B2 + 1e-8f;
    float inv = __builtin_amdgcn_rcpf(den);
    inv = inv * (2.f - den * inv);          // one Newton step
    return (A1 * A2) * inv;
}

// horizontal 7-window sums from per-lane float2 vertical sums, 3 shuffles:
// t = P + P(+1) covers cols 2l..2l+3; S8 = t + t(+2) covers 2l..2l+7;
// even window = S8 - col(2l+7);  odd window = S8 - col(2l).
#define HSUM3(v2, e, o)                                  \
{                                                        \
    float P_ = v2.x + v2.y;                              \
    float t_ = P_ + __shfl_down(P_, 1);                  \
    float S8 = t_ + __shfl_down(t_, 2);                  \
    float o3 = __shfl_down(v2.y, 3);                     \
    e = S8 - o3;                                         \
    o = S8 - v2.x;                                       \
}

#define ROW_BODY(P, I, DOEMIT)                                             \
{                                                                          \
    const int rr   = min(r0 + (I), H - 1);                                 \
    const int rofs = rr * W + cl;                                          \
    const float2 xn = *(const float2*)(Xb + rofs);                         \
    const float2 yn = *(const float2*)(Yb + rofs);                         \
    const float2 xo = rx[P];                                               \
    const float2 yo = ry[P];                                               \
    sx.x  += xn.x - xo.x;            sx.y  += xn.y - xo.y;                 \
    sy.x  += yn.x - yo.x;            sy.y  += yn.y - yo.y;                 \
    sxx.x += xn.x*xn.x - xo.x*xo.x;  sxx.y += xn.y*xn.y - xo.y*xo.y;       \
    syy.x += yn.x*yn.x - yo.x*yo.x;  syy.y += yn.y*yn.y - yo.y*yo.y;       \
    sxy.x += xn.x*yn.x - xo.x*yo.x;  sxy.y += xn.y*yn.y - xo.y*yo.y;       \
    rx[P] = xn; ry[P] = yn;                                                \
    if (DOEMIT) {                                                          \
        const int orow = r0 + (I) - 6;                                     \
        if (orow < OH) {                                                   \
            float ex, oxv, ey, oyv, exx, oxx, eyy, oyy, exy, oxy;          \
            HSUM3(sx,  ex,  oxv)                                           \
            HSUM3(sy,  ey,  oyv)                                           \
            HSUM3(sxx, exx, oxx)                                           \
            HSUM3(syy, eyy, oyy)                                           \
            HSUM3(sxy, exy, oxy)                                           \
            float S0 = ssim_val(ex,  ey,  exx, eyy, exy, w0, C1, C2);      \
            float S1 = ssim_val(oxv, oyv, oxx, oyy, oxy, w0, C1, C2);      \
            acc += (v0ok ? S0 : 0.f) + (v1ok ? S1 : 0.f);                  \
        }                                                                  \
    }                                                                      \
}

__global__ __launch_bounds__(256) void ssim_slide_kernel(
    const float* __restrict__ X, const float* __restrict__ Y,
    const float* __restrict__ dr_p, const float* __restrict__ w_p,
    float* __restrict__ partials)
{
    const int t    = threadIdx.x;
    const int lane = t & 63;
    const int wave = t >> 6;

    // grid: NIMG * NGRP * NBLK blocks; each block = 4 waves = 4 strips
    const int bid = blockIdx.x;
    const int img = bid / (NGRP * NBLK);
    const int rem = bid - img * (NGRP * NBLK);
    const int grp = rem / NBLK;
    const int blk = rem - grp * NBLK;
    const int strip = blk * 4 + wave;           // 0..19
    const int r0    = strip * SOUT;             // first output row of strip

    const int cbase = grp * GRPW;
    const int c0 = cbase + 2 * lane;            // even input col owned by lane
    const int cl = min(c0, W - 2);              // clamp for safe float2 load

    const float* __restrict__ Xb = X + (size_t)img * (H * W);
    const float* __restrict__ Yb = Y + (size_t)img * (H * W);

    const float dr = dr_p[0];
    const float w0 = w_p[0];                    // uniform 1/49 weight
    const float C1 = (0.01f * dr) * (0.01f * dr);
    const float C2 = (0.03f * dr) * (0.03f * dr);

    const bool v0ok = (lane <= 60) && (c0     < OW);
    const bool v1ok = (lane <= 60) && (c0 + 1 < OW);

    float2 rx[7], ry[7];
#pragma unroll
    for (int i = 0; i < 7; ++i) { rx[i] = make_float2(0.f, 0.f); ry[i] = make_float2(0.f, 0.f); }
    float2 sx  = make_float2(0.f, 0.f), sy  = make_float2(0.f, 0.f);
    float2 sxx = make_float2(0.f, 0.f), syy = make_float2(0.f, 0.f);
    float2 sxy = make_float2(0.f, 0.f);
    float acc = 0.f;

    // 22 input rows, phases I%7; rows 6..21 emit output rows r0..r0+15
    ROW_BODY(0, 0,  false)
    ROW_BODY(1, 1,  false)
    ROW_BODY(2, 2,  false)
    ROW_BODY(3, 3,  false)
    ROW_BODY(4, 4,  false)
    ROW_BODY(5, 5,  false)
    ROW_BODY(6, 6,  true)
    ROW_BODY(0, 7,  true)
    ROW_BODY(1, 8,  true)
    ROW_BODY(2, 9,  true)
    ROW_BODY(3, 10, true)
    ROW_BODY(4, 11, true)
    ROW_BODY(5, 12, true)
    ROW_BODY(6, 13, true)
    ROW_BODY(0, 14, true)
    ROW_BODY(1, 15, true)
    ROW_BODY(2, 16, true)
    ROW_BODY(3, 17, true)
    ROW_BODY(4, 18, true)
    ROW_BODY(5, 19, true)
    ROW_BODY(6, 20, true)
    ROW_BODY(0, 21, true)

    // wave reduce
#pragma unroll
    for (int off = 32; off > 0; off >>= 1)
        acc += __shfl_down(acc, off);

    __shared__ float wsum[4];
    if (lane == 0) wsum[wave] = acc;
    __syncthreads();
    if (t == 0) {
        // plain store of the block partial -- NO atomics, NO fence
        partials[bid] = wsum[0] + wsum[1] + wsum[2] + wsum[3];
    }
}

__global__ __launch_bounds__(256) void ssim_reduce_kernel(
    const float* __restrict__ partials, float* __restrict__ out)
{
    const int t = threadIdx.x;
    double s = 0.0;
    for (int i = t; i < NBLOCKS; i += 256) s += (double)partials[i];
#pragma unroll
    for (int off = 32; off > 0; off >>= 1)
        s += __shfl_down(s, off);
    __shared__ double wsum[4];
    const int wave = t >> 6;
    const int lane = t & 63;
    if (lane == 0) wsum[wave] = s;
    __syncthreads();
    if (t == 0) {
        double tot = wsum[0] + wsum[1] + wsum[2] + wsum[3];
        const double cnt = (double)NIMG * (double)(OH * OW);
        out[0] = 1.0f - (float)(tot / cnt);
    }
}

extern "C" void kernel_launch(void* const* d_in, const int* in_sizes, int n_in,
                              void* d_out, int out_size, void* d_ws, size_t ws_size,
                              hipStream_t stream) {
    const float* X  = (const float*)d_in[0];
    const float* Y  = (const float*)d_in[1];
    const float* dr = (const float*)d_in[2];
    const float* w  = (const float*)d_in[3];
    float* partials = (float*)d_ws;            // NBLOCKS floats, all written each call
    float* out      = (float*)d_out;

    ssim_slide_kernel<<<NBLOCKS, 256, 0, stream>>>(X, Y, dr, w, partials);
    ssim_reduce_kernel<<<1, 256, 0, stream>>>(partials, out);
}